// Round 16
// baseline (195.472 us; speedup 1.0000x reference)
//
#include <hip/hip_runtime.h>
#include <hip/hip_bf16.h>

#define B_N 4096
#define D_K 2048
#define RB  1024          /* bytes per fp4 row  (D_K/2) */

typedef __attribute__((ext_vector_type(4))) int   i32x4;
typedef __attribute__((ext_vector_type(8))) int   i32x8;
typedef __attribute__((ext_vector_type(4))) float f32x4;

__device__ __forceinline__ i32x8 mk8(i32x4 lo) {
    return (i32x8){lo[0], lo[1], lo[2], lo[3], 0, 0, 0, 0};
}

__device__ __forceinline__ void gl_lds16(const void* g, void* l) {
    __builtin_amdgcn_global_load_lds(
        (const __attribute__((address_space(1))) unsigned int*)g,
        (__attribute__((address_space(3))) unsigned int*)l,
        16, 0, 0);
}

// e2m1 nibble: {0,0.5,1,1.5,2,3,4,6}, RNE midpoints
__device__ __forceinline__ unsigned int qe2m1(float v) {
    unsigned int s = (__builtin_bit_cast(unsigned int, v) >> 31) << 3;
    float av = fabsf(v);
    unsigned int c = (av >= 0.25f) + (av >= 0.75f) + (av >= 1.25f) + (av >= 1.75f)
                   + (av >= 2.5f)  + (av >= 3.5f)  + (av >= 5.0f);
    return s | c;
}

// ---------------- Kernel 1: row L2-normalize -> fp4 e2m1 (prescaled by 64) + ws zeroing ----------------
__global__ __launch_bounds__(256) void knorm4(const float* __restrict__ C,
                                              const float* __restrict__ S,
                                              unsigned char* __restrict__ Cq,
                                              unsigned char* __restrict__ Sq,
                                              float* __restrict__ rowsum,
                                              float* __restrict__ colsum) {
    int b = blockIdx.x;            // 0..8191
    const float* X;
    unsigned char* Y;
    if (b < B_N) { X = C + (size_t)b * D_K; Y = Cq + (size_t)b * RB; }
    else         { X = S + (size_t)(b - B_N) * D_K; Y = Sq + (size_t)(b - B_N) * RB; }
    int tid = threadIdx.x;

    // zero the accumulators for this call (replaces graph-captured hipMemsetAsync)
    if (tid == 0) {
        if (b < B_N) rowsum[b] = 0.f;
        else         colsum[b - B_N] = 0.f;
    }

    float4 v0 = ((const float4*)X)[tid * 2];
    float4 v1 = ((const float4*)X)[tid * 2 + 1];
    float ss = v0.x*v0.x + v0.y*v0.y + v0.z*v0.z + v0.w*v0.w
             + v1.x*v1.x + v1.y*v1.y + v1.z*v1.z + v1.w*v1.w;
    #pragma unroll
    for (int off = 1; off < 64; off <<= 1) ss += __shfl_xor(ss, off, 64);
    __shared__ float wsum[4];
    if ((tid & 63) == 0) wsum[tid >> 6] = ss;
    __syncthreads();
    float tot = wsum[0] + wsum[1] + wsum[2] + wsum[3];
    // prescale by 64: elements ~N(0,1/D) -> sigma~1.41, e2m1 sweet spot; epilogue /4096
    float inv = 64.f / fmaxf(sqrtf(tot), 1e-12f);

    float vals[8] = { v0.x, v0.y, v0.z, v0.w, v1.x, v1.y, v1.z, v1.w };
    unsigned int u = 0;
    #pragma unroll
    for (int j = 0; j < 8; ++j)
        u |= qe2m1(vals[j] * inv) << (4 * j);   // byte b: elem 2b low nibble, 2b+1 high
    *(unsigned int*)(Y + tid * 4) = u;
}

// ---------------- Kernel 2: 128x128 MX-fp4 GEMM (m153 configuration) + fused epilogue ----------------
// m97/m153 structure: 128^2 tile, 4 waves (2x2), wave tile 64x64, simple 2-barrier loop,
// LDS 32 KB single-buffered -> grid 1024 = 4 blocks/CU (cross-block barrier covering, m114).
// acc = 64 VGPR -> no spill pressure, so NO per-QMMA fences: the compiler pipelines the
// 8-read + 16-MFMA half-window freely (this is what m153's 2878 TF relies on).
// One sched_barrier(0) per k-half bounds the operand live-window (anti-R13 insurance).
// 8-chunk XOR-(row&7) swizzle via pre-swizzled global source + swizzled ds_read.
// mfma_scale_f32_16x16x128_f8f6f4, cbsz=blgp=4 (fp4), data in LOW half, unit scales.

#define SBK 256            /* fp4 elems per stage = 2 K-units */
#define NST (D_K / SBK)    /* 8 stages */

__global__ __launch_bounds__(256, 2) void kgemm_q4(const unsigned char* __restrict__ Aq,
                                                   const unsigned char* __restrict__ Bq,
                                                   const float* __restrict__ temp,
                                                   float* __restrict__ rowsum,
                                                   float* __restrict__ colsum,
                                                   float* __restrict__ diag) {
    __shared__ __align__(16) unsigned char As[128 * 128];   // 16 KB
    __shared__ __align__(16) unsigned char Bs[128 * 128];   // 16 KB

    const int tid  = threadIdx.x;
    const int lane = tid & 63;
    const int wid  = tid >> 6;
    const int wr   = wid >> 1;     // 0..1
    const int wc   = wid & 1;      // 0..1
    const int brow = blockIdx.x * 128;
    const int bcol = blockIdx.y * 128;

    // ---- staging: thread t -> row t>>3 (+32i), chunk t&7; pre-swizzled source chunk ----
    const int srow = tid >> 3;                               // 0..31
    const int sch  = ((tid & 7) ^ (srow & 7)) * 16;          // source byte (pre-swizzle)
    const unsigned char* gA = Aq + (size_t)(brow + srow) * RB + sch;
    const unsigned char* gB = Bq + (size_t)(bcol + srow) * RB + sch;

    // ---- ds_read constants: logical chunk (4h + kq) -> physical ^ (lrow&7) ----
    const int lrow = lane & 15;
    const int kq   = lane >> 4;                              // 0..3
    const int sw   = lrow & 7;
    const int ch0  = ((kq)     ^ sw) * 16;                   // k-half 0
    const int ch1  = ((4 + kq) ^ sw) * 16;                   // k-half 1
    const int abase = (wr * 64 + lrow) * 128;                // + m*2048, m=0..3
    const int bbase = (wc * 64 + lrow) * 128;                // + n*2048, n=0..3

    f32x4 acc[4][4];
    #pragma unroll
    for (int m = 0; m < 4; ++m)
        #pragma unroll
        for (int n = 0; n < 4; ++n) acc[m][n] = (f32x4){0.f, 0.f, 0.f, 0.f};

    for (int st = 0; st < NST; ++st) {
        const int k0b = st * 128;                            // byte offset of stage
        #pragma unroll
        for (int i = 0; i < 4; ++i) {
            gl_lds16(gA + k0b + (size_t)(32 * i) * RB, As + tid * 16 + i * 4096);
            gl_lds16(gB + k0b + (size_t)(32 * i) * RB, Bs + tid * 16 + i * 4096);
        }
        __syncthreads();   // compiler drains vmcnt before barrier

        #pragma unroll
        for (int h = 0; h < 2; ++h) {
            const int ch = h ? ch1 : ch0;
            i32x4 af[4], bf[4];
            #pragma unroll
            for (int m = 0; m < 4; ++m) af[m] = *(const i32x4*)(As + abase + m * 2048 + ch);
            #pragma unroll
            for (int n = 0; n < 4; ++n) bf[n] = *(const i32x4*)(Bs + bbase + n * 2048 + ch);

            #pragma unroll
            for (int m = 0; m < 4; ++m)
                #pragma unroll
                for (int n = 0; n < 4; ++n)
                    acc[m][n] = __builtin_amdgcn_mfma_scale_f32_16x16x128_f8f6f4(
                        mk8(af[m]), mk8(bf[n]), acc[m][n], 4, 4, 0, 127, 0, 127);
            __builtin_amdgcn_sched_barrier(0);   // half boundary: bounds live window
        }
        __syncthreads();
    }

    // ------- epilogue: sim = acc/4096; relu*e^t, shifted exp, row/col sums, diag -------
    const float scl = expf(temp[0]);
    const int rbase = brow + wr * 64;
    const int cbase = bcol + wc * 64 + lrow;
    const int rj = kq * 4;

    float rs[4][4];
    float cs[4];
    #pragma unroll
    for (int m = 0; m < 4; ++m)
        #pragma unroll
        for (int j = 0; j < 4; ++j) rs[m][j] = 0.f;
    #pragma unroll
    for (int n = 0; n < 4; ++n) cs[n] = 0.f;

    #pragma unroll
    for (int m = 0; m < 4; ++m) {
        #pragma unroll
        for (int n = 0; n < 4; ++n) {
            #pragma unroll
            for (int j = 0; j < 4; ++j) {
                float sim = acc[m][n][j] * (1.f / 4096.f);   // undo 64x64 prescale
                float v = fmaxf(sim, 0.f) * scl;
                int gr = rbase + m * 16 + rj + j;
                int gc = cbase + n * 16;
                if (gr == gc) diag[gr] = v;
                float p = expf(v - scl);
                rs[m][j] += p;
                cs[n]    += p;
            }
        }
    }

    #pragma unroll
    for (int m = 0; m < 4; ++m) {
        #pragma unroll
        for (int j = 0; j < 4; ++j) {
            float v = rs[m][j];
            v += __shfl_xor(v, 1, 64);
            v += __shfl_xor(v, 2, 64);
            v += __shfl_xor(v, 4, 64);
            v += __shfl_xor(v, 8, 64);
            if (lrow == 0) atomicAdd(&rowsum[rbase + m * 16 + rj + j], v);
        }
    }
    #pragma unroll
    for (int n = 0; n < 4; ++n) {
        float v = cs[n];
        v += __shfl_xor(v, 16, 64);
        v += __shfl_xor(v, 32, 64);
        if (kq == 0) atomicAdd(&colsum[cbase + n * 16], v);
    }
}

// ---------------- Kernel 3: final reduction to scalar loss ----------------
__global__ __launch_bounds__(256) void kfinal(const float* __restrict__ rowsum,
                                              const float* __restrict__ colsum,
                                              const float* __restrict__ diag,
                                              const float* __restrict__ temp,
                                              float* __restrict__ out) {
    int tid = threadIdx.x;
    float M = expf(temp[0]);
    float acc = 0.f;
    for (int i = tid; i < B_N; i += 256) {
        acc += logf(rowsum[i]) + logf(colsum[i]) + 2.f * M - 2.f * diag[i];
    }
    #pragma unroll
    for (int off = 1; off < 64; off <<= 1) acc += __shfl_xor(acc, off, 64);
    __shared__ float wsum[4];
    if ((tid & 63) == 0) wsum[tid >> 6] = acc;
    __syncthreads();
    if (tid == 0) {
        float t = wsum[0] + wsum[1] + wsum[2] + wsum[3];
        out[0] = t * (0.5f / (float)B_N);
    }
}

extern "C" void kernel_launch(void* const* d_in, const int* in_sizes, int n_in,
                              void* d_out, int out_size, void* d_ws, size_t ws_size,
                              hipStream_t stream) {
    const float* Cf   = (const float*)d_in[0];
    const float* Sf   = (const float*)d_in[1];
    const float* temp = (const float*)d_in[2];

    const size_t MATB = (size_t)B_N * RB;                  // 4 MB per matrix
    unsigned char* Cq = (unsigned char*)d_ws;              // 4 MB
    unsigned char* Sq = Cq + MATB;                         // 4 MB
    float* rowsum = (float*)(Sq + MATB);                   // 16 KB
    float* colsum = rowsum + B_N;
    float* diag   = colsum + B_N;

    knorm4<<<2 * B_N, 256, 0, stream>>>(Cf, Sf, Cq, Sq, rowsum, colsum);
    dim3 grid(B_N / 128, B_N / 128);
    kgemm_q4<<<grid, 256, 0, stream>>>(Cq, Sq, temp, rowsum, colsum, diag);
    kfinal<<<1, 256, 0, stream>>>(rowsum, colsum, diag, temp, (float*)d_out);
}

// Round 17
// 54.539 us; speedup vs baseline: 3.5841x; 3.5841x over previous
//
#include <hip/hip_runtime.h>
#include <hip/hip_bf16.h>

#define B_N 4096
#define D_K 2048
#define RB  1024          /* bytes per fp4 row  (D_K/2) */

typedef __attribute__((ext_vector_type(4))) int   i32x4;
typedef __attribute__((ext_vector_type(8))) int   i32x8;
typedef __attribute__((ext_vector_type(4))) float f32x4;

__device__ __forceinline__ i32x8 mk8(i32x4 lo) {
    return (i32x8){lo[0], lo[1], lo[2], lo[3], 0, 0, 0, 0};
}

__device__ __forceinline__ void gl_lds16(const void* g, void* l) {
    __builtin_amdgcn_global_load_lds(
        (const __attribute__((address_space(1))) unsigned int*)g,
        (__attribute__((address_space(3))) unsigned int*)l,
        16, 0, 0);
}

// e2m1 nibble: {0,0.5,1,1.5,2,3,4,6}, RNE midpoints
__device__ __forceinline__ unsigned int qe2m1(float v) {
    unsigned int s = (__builtin_bit_cast(unsigned int, v) >> 31) << 3;
    float av = fabsf(v);
    unsigned int c = (av >= 0.25f) + (av >= 0.75f) + (av >= 1.25f) + (av >= 1.75f)
                   + (av >= 2.5f)  + (av >= 3.5f)  + (av >= 5.0f);
    return s | c;
}

// ---------------- Kernel 1: row L2-normalize -> fp4 e2m1 (prescaled by 64) + ws zeroing ----------------
__global__ __launch_bounds__(256) void knorm4(const float* __restrict__ C,
                                              const float* __restrict__ S,
                                              unsigned char* __restrict__ Cq,
                                              unsigned char* __restrict__ Sq,
                                              float* __restrict__ rowsum,
                                              float* __restrict__ colsum) {
    int b = blockIdx.x;            // 0..8191
    const float* X;
    unsigned char* Y;
    if (b < B_N) { X = C + (size_t)b * D_K; Y = Cq + (size_t)b * RB; }
    else         { X = S + (size_t)(b - B_N) * D_K; Y = Sq + (size_t)(b - B_N) * RB; }
    int tid = threadIdx.x;

    // zero the accumulators for this call (replaces graph-captured hipMemsetAsync)
    if (tid == 0) {
        if (b < B_N) rowsum[b] = 0.f;
        else         colsum[b - B_N] = 0.f;
    }

    float4 v0 = ((const float4*)X)[tid * 2];
    float4 v1 = ((const float4*)X)[tid * 2 + 1];
    float ss = v0.x*v0.x + v0.y*v0.y + v0.z*v0.z + v0.w*v0.w
             + v1.x*v1.x + v1.y*v1.y + v1.z*v1.z + v1.w*v1.w;
    #pragma unroll
    for (int off = 1; off < 64; off <<= 1) ss += __shfl_xor(ss, off, 64);
    __shared__ float wsum[4];
    if ((tid & 63) == 0) wsum[tid >> 6] = ss;
    __syncthreads();
    float tot = wsum[0] + wsum[1] + wsum[2] + wsum[3];
    // prescale by 64: elements ~N(0,1/D) -> sigma~1.41, e2m1 sweet spot; epilogue /4096
    float inv = 64.f / fmaxf(sqrtf(tot), 1e-12f);

    float vals[8] = { v0.x, v0.y, v0.z, v0.w, v1.x, v1.y, v1.z, v1.w };
    unsigned int u = 0;
    #pragma unroll
    for (int j = 0; j < 8; ++j)
        u |= qe2m1(vals[j] * inv) << (4 * j);   // byte b: elem 2b low nibble, 2b+1 high
    *(unsigned int*)(Y + tid * 4) = u;
}

// ---------------- Kernel 2: 128x256 MX-fp4 GEMM (R12/R14 inner loop, verbatim) + fused epilogue ----------------
// LDS rows 128 B (= 256 fp4 elems = 2 K-units of 128), 8-chunk XOR-(row&7) swizzle via
// pre-swizzled global source + swizzled ds_read, 12 gl_lds/thread/stage, single-buffered
// 48 KB, grid 512 = 2 blocks/CU, 4 waves (N strips), wave tile 128x64.
// Per stage: 2 k-halves x {B resident (4 x i32x4), A streamed one-m-at-a-time}.
// NOTE: the per-QMMA sched_barrier(0) fence is LOAD-BEARING (R8/R13/R16 spill evidence,
// at EVERY tile size): without it the scheduler hoists the half's reads + mk8 tuples and
// the allocator spills acc (WRITE_SIZE 5KB -> 250-330 MB). Do not remove.
// mfma_scale_f32_16x16x128_f8f6f4, cbsz=blgp=4 (fp4), data in LOW half, unit scales.

#define SBK 256            /* fp4 elems per stage = 2 K-units */
#define NST (D_K / SBK)    /* 8 stages */

__global__ __launch_bounds__(256, 2) void kgemm_q4(const unsigned char* __restrict__ Aq,
                                                   const unsigned char* __restrict__ Bq,
                                                   const float* __restrict__ temp,
                                                   float* __restrict__ rowsum,
                                                   float* __restrict__ colsum,
                                                   float* __restrict__ diag) {
    __shared__ __align__(16) unsigned char As[128 * 128];   // 16 KB
    __shared__ __align__(16) unsigned char Bs[256 * 128];   // 32 KB

    const int tid  = threadIdx.x;
    const int lane = tid & 63;
    const int wn   = tid >> 6;     // 0..3: N strip of 64 cols
    const int brow = blockIdx.x * 128;
    const int bcol = blockIdx.y * 256;

    // ---- staging: thread t -> row t>>3 (+32i), chunk t&7; pre-swizzled source chunk ----
    const int srow = tid >> 3;                               // 0..31
    const int sch  = ((tid & 7) ^ (srow & 7)) * 16;          // source byte (pre-swizzle)
    const unsigned char* gA = Aq + (size_t)(brow + srow) * RB + sch;
    const unsigned char* gB = Bq + (size_t)(bcol + srow) * RB + sch;

    // ---- ds_read constants: logical chunk (4h + kq) -> physical ^ (lrow&7) ----
    const int lrow = lane & 15;
    const int kq   = lane >> 4;                              // 0..3
    const int sw   = lrow & 7;
    const int ch0  = ((kq)     ^ sw) * 16;                   // k-half 0
    const int ch1  = ((4 + kq) ^ sw) * 16;                   // k-half 1
    const int abase = lrow * 128;                            // + m*2048, m=0..7
    const int bbase = (wn * 64 + lrow) * 128;                // + n*2048, n=0..3

    f32x4 acc[8][4];
    #pragma unroll
    for (int m = 0; m < 8; ++m)
        #pragma unroll
        for (int n = 0; n < 4; ++n) acc[m][n] = (f32x4){0.f, 0.f, 0.f, 0.f};

    for (int st = 0; st < NST; ++st) {
        const int k0b = st * 128;                            // byte offset of stage
        #pragma unroll
        for (int i = 0; i < 4; ++i)
            gl_lds16(gA + k0b + (size_t)(32 * i) * RB, As + tid * 16 + i * 4096);
        #pragma unroll
        for (int i = 0; i < 8; ++i)
            gl_lds16(gB + k0b + (size_t)(32 * i) * RB, Bs + tid * 16 + i * 4096);
        __syncthreads();   // compiler drains vmcnt before barrier

        #pragma unroll
        for (int h = 0; h < 2; ++h) {
            const int ch = h ? ch1 : ch0;
            // B fragments resident (4 x 4 = 16 VGPR)
            i32x4 b0 = *(const i32x4*)(Bs + bbase + 0 * 2048 + ch);
            i32x4 b1 = *(const i32x4*)(Bs + bbase + 1 * 2048 + ch);
            i32x4 b2 = *(const i32x4*)(Bs + bbase + 2 * 2048 + ch);
            i32x4 b3 = *(const i32x4*)(Bs + bbase + 3 * 2048 + ch);
            __builtin_amdgcn_sched_barrier(0);

            #define QMMA(mm) do { \
                i32x4 a_ = *(const i32x4*)(As + abase + (mm) * 2048 + ch); \
                i32x8 a8 = mk8(a_); \
                acc[mm][0] = __builtin_amdgcn_mfma_scale_f32_16x16x128_f8f6f4( \
                    a8, mk8(b0), acc[mm][0], 4, 4, 0, 127, 0, 127); \
                acc[mm][1] = __builtin_amdgcn_mfma_scale_f32_16x16x128_f8f6f4( \
                    a8, mk8(b1), acc[mm][1], 4, 4, 0, 127, 0, 127); \
                acc[mm][2] = __builtin_amdgcn_mfma_scale_f32_16x16x128_f8f6f4( \
                    a8, mk8(b2), acc[mm][2], 4, 4, 0, 127, 0, 127); \
                acc[mm][3] = __builtin_amdgcn_mfma_scale_f32_16x16x128_f8f6f4( \
                    a8, mk8(b3), acc[mm][3], 4, 4, 0, 127, 0, 127); \
                __builtin_amdgcn_sched_barrier(0); \
            } while (0)

            QMMA(0); QMMA(1); QMMA(2); QMMA(3);
            QMMA(4); QMMA(5); QMMA(6); QMMA(7);
            #undef QMMA
        }
        __syncthreads();
    }

    // ------- epilogue: sim = acc/4096; relu*e^t, shifted exp, row/col sums, diag -------
    const float scl = expf(temp[0]);
    const int cbase = bcol + wn * 64 + lrow;   // + n*16
    const int rj = kq * 4;

    float cs[4] = {0.f, 0.f, 0.f, 0.f};
    #pragma unroll
    for (int m = 0; m < 8; ++m) {
        float rs[4] = {0.f, 0.f, 0.f, 0.f};
        #pragma unroll
        for (int n = 0; n < 4; ++n) {
            #pragma unroll
            for (int j = 0; j < 4; ++j) {
                float sim = acc[m][n][j] * (1.f / 4096.f);   // undo 64x64 prescale
                float v = fmaxf(sim, 0.f) * scl;
                int gr = brow + m * 16 + rj + j;
                int gc = cbase + n * 16;
                if (gr == gc) diag[gr] = v;
                float p = expf(v - scl);
                rs[j]  += p;
                cs[n]  += p;
            }
        }
        #pragma unroll
        for (int j = 0; j < 4; ++j) {
            float v = rs[j];
            v += __shfl_xor(v, 1, 64);
            v += __shfl_xor(v, 2, 64);
            v += __shfl_xor(v, 4, 64);
            v += __shfl_xor(v, 8, 64);
            if (lrow == 0) atomicAdd(&rowsum[brow + m * 16 + rj + j], v);
        }
    }
    #pragma unroll
    for (int n = 0; n < 4; ++n) {
        float v = cs[n];
        v += __shfl_xor(v, 16, 64);
        v += __shfl_xor(v, 32, 64);
        if (kq == 0) atomicAdd(&colsum[cbase + n * 16], v);
    }
}

// ---------------- Kernel 3: final reduction to scalar loss ----------------
__global__ __launch_bounds__(256) void kfinal(const float* __restrict__ rowsum,
                                              const float* __restrict__ colsum,
                                              const float* __restrict__ diag,
                                              const float* __restrict__ temp,
                                              float* __restrict__ out) {
    int tid = threadIdx.x;
    float M = expf(temp[0]);
    float acc = 0.f;
    for (int i = tid; i < B_N; i += 256) {
        acc += logf(rowsum[i]) + logf(colsum[i]) + 2.f * M - 2.f * diag[i];
    }
    #pragma unroll
    for (int off = 1; off < 64; off <<= 1) acc += __shfl_xor(acc, off, 64);
    __shared__ float wsum[4];
    if ((tid & 63) == 0) wsum[tid >> 6] = acc;
    __syncthreads();
    if (tid == 0) {
        float t = wsum[0] + wsum[1] + wsum[2] + wsum[3];
        out[0] = t * (0.5f / (float)B_N);
    }
}

extern "C" void kernel_launch(void* const* d_in, const int* in_sizes, int n_in,
                              void* d_out, int out_size, void* d_ws, size_t ws_size,
                              hipStream_t stream) {
    const float* Cf   = (const float*)d_in[0];
    const float* Sf   = (const float*)d_in[1];
    const float* temp = (const float*)d_in[2];

    const size_t MATB = (size_t)B_N * RB;                  // 4 MB per matrix
    unsigned char* Cq = (unsigned char*)d_ws;              // 4 MB
    unsigned char* Sq = Cq + MATB;                         // 4 MB
    float* rowsum = (float*)(Sq + MATB);                   // 16 KB
    float* colsum = rowsum + B_N;
    float* diag   = colsum + B_N;

    knorm4<<<2 * B_N, 256, 0, stream>>>(Cf, Sf, Cq, Sq, rowsum, colsum);
    dim3 grid(B_N / 128, B_N / 256);
    kgemm_q4<<<grid, 256, 0, stream>>>(Cq, Sq, temp, rowsum, colsum, diag);
    kfinal<<<1, 256, 0, stream>>>(rowsum, colsum, diag, temp, (float*)d_out);
}

// Round 18
// 54.453 us; speedup vs baseline: 3.5897x; 1.0016x over previous
//
#include <hip/hip_runtime.h>
#include <hip/hip_bf16.h>

#define B_N 4096
#define D_K 2048
#define RB  1024          /* bytes per fp4 row  (D_K/2) */

typedef __attribute__((ext_vector_type(4))) int   i32x4;
typedef __attribute__((ext_vector_type(8))) int   i32x8;
typedef __attribute__((ext_vector_type(4))) float f32x4;

__device__ __forceinline__ i32x8 mk8(i32x4 lo) {
    return (i32x8){lo[0], lo[1], lo[2], lo[3], 0, 0, 0, 0};
}

__device__ __forceinline__ void gl_lds16(const void* g, void* l) {
    __builtin_amdgcn_global_load_lds(
        (const __attribute__((address_space(1))) unsigned int*)g,
        (__attribute__((address_space(3))) unsigned int*)l,
        16, 0, 0);
}

// e2m1 nibble: {0,0.5,1,1.5,2,3,4,6}, RNE midpoints
__device__ __forceinline__ unsigned int qe2m1(float v) {
    unsigned int s = (__builtin_bit_cast(unsigned int, v) >> 31) << 3;
    float av = fabsf(v);
    unsigned int c = (av >= 0.25f) + (av >= 0.75f) + (av >= 1.25f) + (av >= 1.75f)
                   + (av >= 2.5f)  + (av >= 3.5f)  + (av >= 5.0f);
    return s | c;
}

// ---------------- Kernel 1: row L2-normalize -> fp4 e2m1 (prescaled by 64) + ws zeroing ----------------
__global__ __launch_bounds__(256) void knorm4(const float* __restrict__ C,
                                              const float* __restrict__ S,
                                              unsigned char* __restrict__ Cq,
                                              unsigned char* __restrict__ Sq,
                                              float* __restrict__ rowsum,
                                              float* __restrict__ colsum) {
    int b = blockIdx.x;            // 0..8191
    const float* X;
    unsigned char* Y;
    if (b < B_N) { X = C + (size_t)b * D_K; Y = Cq + (size_t)b * RB; }
    else         { X = S + (size_t)(b - B_N) * D_K; Y = Sq + (size_t)(b - B_N) * RB; }
    int tid = threadIdx.x;

    // zero the accumulators for this call (replaces graph-captured hipMemsetAsync)
    if (tid == 0) {
        if (b < B_N) rowsum[b] = 0.f;
        else         colsum[b - B_N] = 0.f;
    }

    float4 v0 = ((const float4*)X)[tid * 2];
    float4 v1 = ((const float4*)X)[tid * 2 + 1];
    float ss = v0.x*v0.x + v0.y*v0.y + v0.z*v0.z + v0.w*v0.w
             + v1.x*v1.x + v1.y*v1.y + v1.z*v1.z + v1.w*v1.w;
    #pragma unroll
    for (int off = 1; off < 64; off <<= 1) ss += __shfl_xor(ss, off, 64);
    __shared__ float wsum[4];
    if ((tid & 63) == 0) wsum[tid >> 6] = ss;
    __syncthreads();
    float tot = wsum[0] + wsum[1] + wsum[2] + wsum[3];
    // prescale by 64: elements ~N(0,1/D) -> sigma~1.41, e2m1 sweet spot; epilogue /4096
    float inv = 64.f / fmaxf(sqrtf(tot), 1e-12f);

    float vals[8] = { v0.x, v0.y, v0.z, v0.w, v1.x, v1.y, v1.z, v1.w };
    unsigned int u = 0;
    #pragma unroll
    for (int j = 0; j < 8; ++j)
        u |= qe2m1(vals[j] * inv) << (4 * j);   // byte b: elem 2b low nibble, 2b+1 high
    *(unsigned int*)(Y + tid * 4) = u;
}

// ---------------- Kernel 2: 128x256 MX-fp4 GEMM + fused epilogue ----------------
// R14/R17 structure; ONE change: fence granularity 1-m -> 2-m regions.
// Each region: 2 ds_reads (A[mm], A[mm+1]) + 8 MFMA + sched_barrier(0).
// Halves exposed-latency-to-MFMA ratio vs 1-m; bounded live window grows ~8 VGPR.
// B stays i32x4-resident with mk8-at-use (R13's spill came from i32x8-resident B +
// batch-materialized 4-tuple A groups; 2-m with mk8-at-use stays under budget).
// TRIPWIRE: WRITE_SIZE >> 5 KB or dur regress -> revert to R17 kernel and declare.
// mfma_scale_f32_16x16x128_f8f6f4, cbsz=blgp=4 (fp4), data in LOW half, unit scales.

#define SBK 256            /* fp4 elems per stage = 2 K-units */
#define NST (D_K / SBK)    /* 8 stages */

__global__ __launch_bounds__(256, 2) void kgemm_q4(const unsigned char* __restrict__ Aq,
                                                   const unsigned char* __restrict__ Bq,
                                                   const float* __restrict__ temp,
                                                   float* __restrict__ rowsum,
                                                   float* __restrict__ colsum,
                                                   float* __restrict__ diag) {
    __shared__ __align__(16) unsigned char As[128 * 128];   // 16 KB
    __shared__ __align__(16) unsigned char Bs[256 * 128];   // 32 KB

    const int tid  = threadIdx.x;
    const int lane = tid & 63;
    const int wn   = tid >> 6;     // 0..3: N strip of 64 cols
    const int brow = blockIdx.x * 128;
    const int bcol = blockIdx.y * 256;

    // ---- staging: thread t -> row t>>3 (+32i), chunk t&7; pre-swizzled source chunk ----
    const int srow = tid >> 3;                               // 0..31
    const int sch  = ((tid & 7) ^ (srow & 7)) * 16;          // source byte (pre-swizzle)
    const unsigned char* gA = Aq + (size_t)(brow + srow) * RB + sch;
    const unsigned char* gB = Bq + (size_t)(bcol + srow) * RB + sch;

    // ---- ds_read constants: logical chunk (4h + kq) -> physical ^ (lrow&7) ----
    const int lrow = lane & 15;
    const int kq   = lane >> 4;                              // 0..3
    const int sw   = lrow & 7;
    const int ch0  = ((kq)     ^ sw) * 16;                   // k-half 0
    const int ch1  = ((4 + kq) ^ sw) * 16;                   // k-half 1
    const int abase = lrow * 128;                            // + m*2048, m=0..7
    const int bbase = (wn * 64 + lrow) * 128;                // + n*2048, n=0..3

    f32x4 acc[8][4];
    #pragma unroll
    for (int m = 0; m < 8; ++m)
        #pragma unroll
        for (int n = 0; n < 4; ++n) acc[m][n] = (f32x4){0.f, 0.f, 0.f, 0.f};

    for (int st = 0; st < NST; ++st) {
        const int k0b = st * 128;                            // byte offset of stage
        #pragma unroll
        for (int i = 0; i < 4; ++i)
            gl_lds16(gA + k0b + (size_t)(32 * i) * RB, As + tid * 16 + i * 4096);
        #pragma unroll
        for (int i = 0; i < 8; ++i)
            gl_lds16(gB + k0b + (size_t)(32 * i) * RB, Bs + tid * 16 + i * 4096);
        __syncthreads();   // compiler drains vmcnt before barrier

        #pragma unroll
        for (int h = 0; h < 2; ++h) {
            const int ch = h ? ch1 : ch0;
            // B fragments resident (4 x 4 = 16 VGPR)
            i32x4 b0 = *(const i32x4*)(Bs + bbase + 0 * 2048 + ch);
            i32x4 b1 = *(const i32x4*)(Bs + bbase + 1 * 2048 + ch);
            i32x4 b2 = *(const i32x4*)(Bs + bbase + 2 * 2048 + ch);
            i32x4 b3 = *(const i32x4*)(Bs + bbase + 3 * 2048 + ch);
            __builtin_amdgcn_sched_barrier(0);

            // 2-m region: 2 A reads + 8 MFMA per fence window
            #define QMMA2(mm) do { \
                i32x4 a0_ = *(const i32x4*)(As + abase + (mm) * 2048 + ch); \
                i32x4 a1_ = *(const i32x4*)(As + abase + ((mm) + 1) * 2048 + ch); \
                i32x8 a80 = mk8(a0_); \
                acc[mm][0] = __builtin_amdgcn_mfma_scale_f32_16x16x128_f8f6f4( \
                    a80, mk8(b0), acc[mm][0], 4, 4, 0, 127, 0, 127); \
                acc[mm][1] = __builtin_amdgcn_mfma_scale_f32_16x16x128_f8f6f4( \
                    a80, mk8(b1), acc[mm][1], 4, 4, 0, 127, 0, 127); \
                acc[mm][2] = __builtin_amdgcn_mfma_scale_f32_16x16x128_f8f6f4( \
                    a80, mk8(b2), acc[mm][2], 4, 4, 0, 127, 0, 127); \
                acc[mm][3] = __builtin_amdgcn_mfma_scale_f32_16x16x128_f8f6f4( \
                    a80, mk8(b3), acc[mm][3], 4, 4, 0, 127, 0, 127); \
                i32x8 a81 = mk8(a1_); \
                acc[(mm)+1][0] = __builtin_amdgcn_mfma_scale_f32_16x16x128_f8f6f4( \
                    a81, mk8(b0), acc[(mm)+1][0], 4, 4, 0, 127, 0, 127); \
                acc[(mm)+1][1] = __builtin_amdgcn_mfma_scale_f32_16x16x128_f8f6f4( \
                    a81, mk8(b1), acc[(mm)+1][1], 4, 4, 0, 127, 0, 127); \
                acc[(mm)+1][2] = __builtin_amdgcn_mfma_scale_f32_16x16x128_f8f6f4( \
                    a81, mk8(b2), acc[(mm)+1][2], 4, 4, 0, 127, 0, 127); \
                acc[(mm)+1][3] = __builtin_amdgcn_mfma_scale_f32_16x16x128_f8f6f4( \
                    a81, mk8(b3), acc[(mm)+1][3], 4, 4, 0, 127, 0, 127); \
                __builtin_amdgcn_sched_barrier(0); \
            } while (0)

            QMMA2(0); QMMA2(2); QMMA2(4); QMMA2(6);
            #undef QMMA2
        }
        __syncthreads();
    }

    // ------- epilogue: sim = acc/4096; relu*e^t, shifted exp, row/col sums, diag -------
    const float scl = expf(temp[0]);
    const int cbase = bcol + wn * 64 + lrow;   // + n*16
    const int rj = kq * 4;

    float cs[4] = {0.f, 0.f, 0.f, 0.f};
    #pragma unroll
    for (int m = 0; m < 8; ++m) {
        float rs[4] = {0.f, 0.f, 0.f, 0.f};
        #pragma unroll
        for (int n = 0; n < 4; ++n) {
            #pragma unroll
            for (int j = 0; j < 4; ++j) {
                float sim = acc[m][n][j] * (1.f / 4096.f);   // undo 64x64 prescale
                float v = fmaxf(sim, 0.f) * scl;
                int gr = brow + m * 16 + rj + j;
                int gc = cbase + n * 16;
                if (gr == gc) diag[gr] = v;
                float p = expf(v - scl);
                rs[j]  += p;
                cs[n]  += p;
            }
        }
        #pragma unroll
        for (int j = 0; j < 4; ++j) {
            float v = rs[j];
            v += __shfl_xor(v, 1, 64);
            v += __shfl_xor(v, 2, 64);
            v += __shfl_xor(v, 4, 64);
            v += __shfl_xor(v, 8, 64);
            if (lrow == 0) atomicAdd(&rowsum[brow + m * 16 + rj + j], v);
        }
    }
    #pragma unroll
    for (int n = 0; n < 4; ++n) {
        float v = cs[n];
        v += __shfl_xor(v, 16, 64);
        v += __shfl_xor(v, 32, 64);
        if (kq == 0) atomicAdd(&colsum[cbase + n * 16], v);
    }
}

// ---------------- Kernel 3: final reduction to scalar loss ----------------
__global__ __launch_bounds__(256) void kfinal(const float* __restrict__ rowsum,
                                              const float* __restrict__ colsum,
                                              const float* __restrict__ diag,
                                              const float* __restrict__ temp,
                                              float* __restrict__ out) {
    int tid = threadIdx.x;
    float M = expf(temp[0]);
    float acc = 0.f;
    for (int i = tid; i < B_N; i += 256) {
        acc += logf(rowsum[i]) + logf(colsum[i]) + 2.f * M - 2.f * diag[i];
    }
    #pragma unroll
    for (int off = 1; off < 64; off <<= 1) acc += __shfl_xor(acc, off, 64);
    __shared__ float wsum[4];
    if ((tid & 63) == 0) wsum[tid >> 6] = acc;
    __syncthreads();
    if (tid == 0) {
        float t = wsum[0] + wsum[1] + wsum[2] + wsum[3];
        out[0] = t * (0.5f / (float)B_N);
    }
}

extern "C" void kernel_launch(void* const* d_in, const int* in_sizes, int n_in,
                              void* d_out, int out_size, void* d_ws, size_t ws_size,
                              hipStream_t stream) {
    const float* Cf   = (const float*)d_in[0];
    const float* Sf   = (const float*)d_in[1];
    const float* temp = (const float*)d_in[2];

    const size_t MATB = (size_t)B_N * RB;                  // 4 MB per matrix
    unsigned char* Cq = (unsigned char*)d_ws;              // 4 MB
    unsigned char* Sq = Cq + MATB;                         // 4 MB
    float* rowsum = (float*)(Sq + MATB);                   // 16 KB
    float* colsum = rowsum + B_N;
    float* diag   = colsum + B_N;

    knorm4<<<2 * B_N, 256, 0, stream>>>(Cf, Sf, Cq, Sq, rowsum, colsum);
    dim3 grid(B_N / 128, B_N / 256);
    kgemm_q4<<<grid, 256, 0, stream>>>(Cq, Sq, temp, rowsum, colsum, diag);
    kfinal<<<1, 256, 0, stream>>>(rowsum, colsum, diag, temp, (float*)d_out);
}